// Round 2
// baseline (1060.130 us; speedup 1.0000x reference)
//
#include <hip/hip_runtime.h>
#include <stdint.h>

typedef __attribute__((ext_vector_type(4))) float f32x4;
typedef __attribute__((ext_vector_type(8))) __bf16 bf16x8;
typedef __attribute__((ext_vector_type(4))) uint16_t u16x4;

#define CDIM 1024
#define K3   3072
#define LSEQ 13
#define NTOK 4096

__device__ __forceinline__ uint16_t f2bf(float x){
  union { float f; uint32_t u; } c; c.f = x;
  uint32_t r = (c.u + 0x7FFFu + ((c.u >> 16) & 1u)) >> 16;
  return (uint16_t)r;
}
__device__ __forceinline__ float bf2f(uint16_t h){
  union { uint32_t u; float f; } c; c.u = ((uint32_t)h) << 16;
  return c.f;
}

__device__ __forceinline__ void async16(const void* g, void* l){
  __builtin_amdgcn_global_load_lds((__attribute__((address_space(1))) void*)(g),
                                   (__attribute__((address_space(3))) void*)(l), 16, 0, 0);
}

// ---------------- conversion kernels ----------------

// W (1024x1024 fp32, row j = output col, k contiguous) -> W3 [1024][3072] bf16 = [hi | hi | lo]
__global__ void convert_W(const float* __restrict__ W, uint16_t* __restrict__ W3){
  int idx = blockIdx.x * 256 + threadIdx.x;          // 262144 threads, 4 elems each
  int j = idx >> 8;
  int c4 = (idx & 255) * 4;
  float4 v = *(const float4*)(W + (size_t)j * CDIM + c4);
  u16x4 h, lo;
  h.x = f2bf(v.x); lo.x = f2bf(v.x - bf2f(h.x));
  h.y = f2bf(v.y); lo.y = f2bf(v.y - bf2f(h.y));
  h.z = f2bf(v.z); lo.z = f2bf(v.z - bf2f(h.z));
  h.w = f2bf(v.w); lo.w = f2bf(v.w - bf2f(h.w));
  uint16_t* r = W3 + (size_t)j * K3;
  *(u16x4*)(r + c4)        = h;
  *(u16x4*)(r + 1024 + c4) = h;
  *(u16x4*)(r + 2048 + c4) = lo;
}

// RoPE tables: cos/sin[l*32+i] = cos/sin(l / 10000^(2i/64))
__global__ void rope_table(float* __restrict__ cosT, float* __restrict__ sinT){
  int t = threadIdx.x;
  if (t < LSEQ * 32){
    int l = t >> 5, i = t & 31;
    float inv = 1.0f / powf(10000.0f, ((float)(2 * i)) / 64.0f);
    float a = (float)l * inv;
    cosT[t] = cosf(a);
    sinT[t] = sinf(a);
  }
}

// A chunk: seq[n, l, c] = layer_outputs[l*(4096*1024) + n*1024 + c] -> hi/lo bf16 rows (n_local*13 + l)
__global__ void convert_A(const float* __restrict__ src, uint16_t* __restrict__ Ah,
                          uint16_t* __restrict__ Al, int n0){
  int idx = blockIdx.x * 256 + threadIdx.x;
  int row = idx >> 8;                    // local row = n_local*13 + l
  int c4 = (idx & 255) * 4;
  int nl = row / 13;
  int l  = row - nl * 13;
  float4 v = *(const float4*)(src + (size_t)l * (NTOK * CDIM) + (size_t)(n0 + nl) * CDIM + c4);
  u16x4 h, lo;
  h.x = f2bf(v.x); lo.x = f2bf(v.x - bf2f(h.x));
  h.y = f2bf(v.y); lo.y = f2bf(v.y - bf2f(h.y));
  h.z = f2bf(v.z); lo.z = f2bf(v.z - bf2f(h.z));
  h.w = f2bf(v.w); lo.w = f2bf(v.w - bf2f(h.w));
  *(u16x4*)(Ah + (size_t)row * CDIM + c4) = h;
  *(u16x4*)(Al + (size_t)row * CDIM + c4) = lo;
}

// Q input rows: only l = 12
__global__ void convert_Aq(const float* __restrict__ src, uint16_t* __restrict__ Ah,
                           uint16_t* __restrict__ Al){
  int idx = blockIdx.x * 256 + threadIdx.x;
  int n = idx >> 8;
  int c4 = (idx & 255) * 4;
  float4 v = *(const float4*)(src + (size_t)12 * (NTOK * CDIM) + (size_t)n * CDIM + c4);
  u16x4 h, lo;
  h.x = f2bf(v.x); lo.x = f2bf(v.x - bf2f(h.x));
  h.y = f2bf(v.y); lo.y = f2bf(v.y - bf2f(h.y));
  h.z = f2bf(v.z); lo.z = f2bf(v.z - bf2f(h.z));
  h.w = f2bf(v.w); lo.w = f2bf(v.w - bf2f(h.w));
  *(u16x4*)(Ah + (size_t)n * CDIM + c4) = h;
  *(u16x4*)(Al + (size_t)n * CDIM + c4) = lo;
}

// ---------------- bf16x3 GEMM ----------------
// C[r][j] = sum_k A[r][k]*W[j][k] in ~fp32 precision.
// Virtual K=3072: phase0 A_hi*B_hi, phase1 A_lo*B_hi, phase2 A_hi*B_lo; B3 = [hi|hi|lo].
// 128x128 tile, BK=64, 4 waves (2x2), 16x16x32 bf16 MFMA, global_load_lds w=16,
// XOR-swizzled LDS via pre-swizzled global source (byte-slot ^= row&7).
__global__ __launch_bounds__(256, 2)
void gemm_x3(const uint16_t* __restrict__ Ahi, const uint16_t* __restrict__ Alo,
             const uint16_t* __restrict__ B3, float* __restrict__ Cout)
{
  __shared__ __align__(16) uint16_t sA[128 * 64];
  __shared__ __align__(16) uint16_t sB[128 * 64];
  const int tid  = threadIdx.x;
  const int lane = tid & 63;
  const int wave = tid >> 6;
  const int arow0 = blockIdx.x * 128;
  const int bcol0 = blockIdx.y * 128;
  const int wr = (wave >> 1) * 64;
  const int wc = (wave & 1) * 64;

  const f32x4 fzero = {0.f, 0.f, 0.f, 0.f};
  f32x4 acc[4][4];
#pragma unroll
  for (int i = 0; i < 4; ++i)
#pragma unroll
    for (int j = 0; j < 4; ++j)
      acc[i][j] = fzero;

  // staging: 1024 16B-units per tile; instruction i covers units i*256 + tid
  size_t aOff[4], bOff[4];
  int ldsOff[4];
#pragma unroll
  for (int i = 0; i < 4; ++i){
    int o = i * 256 + tid;
    int row = o >> 3;
    int ss = (o & 7) ^ (row & 7);              // pre-swizzled source slot
    aOff[i] = (size_t)(arow0 + row) * CDIM + ss * 8;
    bOff[i] = (size_t)(bcol0 + row) * K3 + ss * 8;
    ldsOff[i] = (i * 256 + wave * 64) * 16;    // wave-uniform LDS base
  }

  // fragment ds_read offsets (row&7 == lane&7 for all sub-tiles)
  int aRd[2][4], bRd[2][4];
#pragma unroll
  for (int ks = 0; ks < 2; ++ks){
    int sw = ((lane >> 4) + ks * 4) ^ (lane & 7);
#pragma unroll
    for (int mi = 0; mi < 4; ++mi){
      int ar = wr + mi * 16 + (lane & 15);
      aRd[ks][mi] = ar * 128 + sw * 16;
      int br = wc + mi * 16 + (lane & 15);
      bRd[ks][mi] = br * 128 + sw * 16;
    }
  }

  const char* sAc = (const char*)sA;
  const char* sBc = (const char*)sB;

  for (int step = 0; step < K3 / 64; ++step){
    const int kv0 = step * 64;
    const uint16_t* Abase = ((kv0 >> 10) == 1) ? Alo : Ahi;  // phase 1 -> A_lo
    const int kr0 = kv0 & 1023;
#pragma unroll
    for (int i = 0; i < 4; ++i){
      async16(Abase + aOff[i] + kr0, (char*)sA + ldsOff[i]);
      async16(B3    + bOff[i] + kv0, (char*)sB + ldsOff[i]);
    }
    __syncthreads();   // drains vmcnt: staged data visible
#pragma unroll
    for (int ks = 0; ks < 2; ++ks){
      bf16x8 af[4], bfr[4];
#pragma unroll
      for (int mi = 0; mi < 4; ++mi) af[mi]  = *(const bf16x8*)(sAc + aRd[ks][mi]);
#pragma unroll
      for (int ni = 0; ni < 4; ++ni) bfr[ni] = *(const bf16x8*)(sBc + bRd[ks][ni]);
#pragma unroll
      for (int mi = 0; mi < 4; ++mi)
#pragma unroll
        for (int ni = 0; ni < 4; ++ni)
          acc[mi][ni] = __builtin_amdgcn_mfma_f32_16x16x32_bf16(af[mi], bfr[ni], acc[mi][ni], 0, 0, 0);
    }
    __syncthreads();   // all reads done before next stage overwrites
  }

#pragma unroll
  for (int mi = 0; mi < 4; ++mi){
    const int row = arow0 + wr + mi * 16 + (lane >> 4) * 4;
#pragma unroll
    for (int r = 0; r < 4; ++r){
      float* crow = Cout + (size_t)(row + r) * CDIM + bcol0 + wc + (lane & 15);
#pragma unroll
      for (int ni = 0; ni < 4; ++ni)
        crow[ni * 16] = acc[mi][ni][r];
    }
  }
}

// ---------------- fused RoPE + attention (l = 12 query only) ----------------
// one wave per (token, head); D=64 -> lane = d
__global__ void attn_kernel(const float* __restrict__ Kb, const float* __restrict__ Vb,
                            const float* __restrict__ q, const float* __restrict__ cosT,
                            const float* __restrict__ sinT, uint16_t* __restrict__ ohi,
                            uint16_t* __restrict__ olo, int n0)
{
  int wid  = blockIdx.x * 4 + (threadIdx.x >> 6);
  int lane = threadIdx.x & 63;
  int nl = wid >> 4;           // chunk-local token
  int h  = wid & 15;
  int d = lane, i = d & 31;

  size_t qoff = (size_t)(n0 + nl) * CDIM + h * 64 + d;
  float qv = q[qoff];
  float qp = __shfl_xor(qv, 32);
  float cq = cosT[12 * 32 + i], sq = sinT[12 * 32 + i];
  float qr = (d < 32) ? (qv * cq - qp * sq) : (qv * cq + qp * sq);

  const float* Kp = Kb + (size_t)nl * (LSEQ * CDIM) + h * 64 + d;
  const float* Vp = Vb + (size_t)nl * (LSEQ * CDIM) + h * 64 + d;

  float s[LSEQ];
#pragma unroll
  for (int m = 0; m < LSEQ; ++m){
    float kv = Kp[m * CDIM];
    float kp = __shfl_xor(kv, 32);
    float cm = cosT[m * 32 + i], sm = sinT[m * 32 + i];
    float kr = (d < 32) ? (kv * cm - kp * sm) : (kv * cm + kp * sm);
    float p = qr * kr;
    p += __shfl_xor(p, 32); p += __shfl_xor(p, 16); p += __shfl_xor(p, 8);
    p += __shfl_xor(p, 4);  p += __shfl_xor(p, 2);  p += __shfl_xor(p, 1);
    s[m] = p * 0.125f;       // 1/sqrt(64)
  }
  float mx = s[0];
#pragma unroll
  for (int m = 1; m < LSEQ; ++m) mx = fmaxf(mx, s[m]);
  float sum = 0.f;
#pragma unroll
  for (int m = 0; m < LSEQ; ++m){ s[m] = expf(s[m] - mx); sum += s[m]; }
  float inv = 1.0f / sum;
  float o = 0.f;
#pragma unroll
  for (int m = 0; m < LSEQ; ++m) o += s[m] * Vp[m * CDIM];
  o *= inv;
  uint16_t hb = f2bf(o);
  uint16_t lb = f2bf(o - bf2f(hb));
  ohi[qoff] = hb;
  olo[qoff] = lb;
}

// ---------------- host ----------------
extern "C" void kernel_launch(void* const* d_in, const int* in_sizes, int n_in,
                              void* d_out, int out_size, void* d_ws, size_t ws_size,
                              hipStream_t stream)
{
  (void)in_sizes; (void)n_in; (void)out_size;
  const float* src = (const float*)d_in[0];
  const float* Wq  = (const float*)d_in[1];
  const float* Wk  = (const float*)d_in[2];
  const float* Wv  = (const float*)d_in[3];
  const float* Wo  = (const float*)d_in[4];
  float* out = (float*)d_out;

  // adaptive chunk over tokens: footprint = fixed (~72MB) + cn*159744
  // (cn must stay >=128 so cn*13 divides by the 128-row GEMM tile)
  int cn = 1024;
  while (cn > 128 && (75501056ull + 4096ull + (size_t)cn * 159744ull) > ws_size) cn >>= 1;
  const int nchunks = NTOK / cn;

  char* p = (char*)d_ws;
  auto carve = [&](size_t bytes) -> void* {
    void* r = (void*)p; p += (bytes + 255) & ~(size_t)255; return r;
  };
  uint16_t* W3q = (uint16_t*)carve((size_t)CDIM * K3 * 2);
  uint16_t* W3k = (uint16_t*)carve((size_t)CDIM * K3 * 2);
  uint16_t* W3v = (uint16_t*)carve((size_t)CDIM * K3 * 2);
  uint16_t* W3o = (uint16_t*)carve((size_t)CDIM * K3 * 2);
  float* cosT = (float*)carve(LSEQ * 32 * 4);
  float* sinT = (float*)carve(LSEQ * 32 * 4);
  uint16_t* Aqh = (uint16_t*)carve((size_t)NTOK * CDIM * 2);
  uint16_t* Aql = (uint16_t*)carve((size_t)NTOK * CDIM * 2);
  float* qbuf   = (float*)carve((size_t)NTOK * CDIM * 4);
  uint16_t* ohi = (uint16_t*)carve((size_t)NTOK * CDIM * 2);
  uint16_t* olo = (uint16_t*)carve((size_t)NTOK * CDIM * 2);
  uint16_t* Ah  = (uint16_t*)carve((size_t)cn * LSEQ * CDIM * 2);
  uint16_t* Al  = (uint16_t*)carve((size_t)cn * LSEQ * CDIM * 2);
  float* Kb     = (float*)carve((size_t)cn * LSEQ * CDIM * 4);
  float* Vb     = (float*)carve((size_t)cn * LSEQ * CDIM * 4);

  convert_W<<<1024, 256, 0, stream>>>(Wq, W3q);
  convert_W<<<1024, 256, 0, stream>>>(Wk, W3k);
  convert_W<<<1024, 256, 0, stream>>>(Wv, W3v);
  convert_W<<<1024, 256, 0, stream>>>(Wo, W3o);
  rope_table<<<1, 512, 0, stream>>>(cosT, sinT);
  convert_Aq<<<NTOK, 256, 0, stream>>>(src, Aqh, Aql);
  gemm_x3<<<dim3(NTOK / 128, 8), 256, 0, stream>>>(Aqh, Aql, W3q, qbuf);

  for (int c = 0; c < nchunks; ++c){
    convert_A<<<cn * LSEQ, 256, 0, stream>>>(src, Ah, Al, c * cn);
    gemm_x3<<<dim3(cn * LSEQ / 128, 8), 256, 0, stream>>>(Ah, Al, W3k, Kb);
    gemm_x3<<<dim3(cn * LSEQ / 128, 8), 256, 0, stream>>>(Ah, Al, W3v, Vb);
    attn_kernel<<<cn * 4, 256, 0, stream>>>(Kb, Vb, qbuf, cosT, sinT, ohi, olo, c * cn);
  }
  gemm_x3<<<dim3(NTOK / 128, 8), 256, 0, stream>>>(ohi, olo, W3o, out);
}

// Round 3
// 939.634 us; speedup vs baseline: 1.1282x; 1.1282x over previous
//
#include <hip/hip_runtime.h>
#include <stdint.h>

typedef __attribute__((ext_vector_type(4))) float f32x4;
typedef __attribute__((ext_vector_type(8))) __bf16 bf16x8;
typedef __attribute__((ext_vector_type(4))) uint16_t u16x4;

#define CDIM 1024
#define K3   3072
#define LSEQ 13
#define NTOK 4096

__device__ __forceinline__ uint16_t f2bf(float x){
  union { float f; uint32_t u; } c; c.f = x;
  uint32_t r = (c.u + 0x7FFFu + ((c.u >> 16) & 1u)) >> 16;
  return (uint16_t)r;
}
__device__ __forceinline__ float bf2f(uint16_t h){
  union { uint32_t u; float f; } c; c.u = ((uint32_t)h) << 16;
  return c.f;
}

__device__ __forceinline__ void async16(const void* g, void* l){
  __builtin_amdgcn_global_load_lds((__attribute__((address_space(1))) void*)(g),
                                   (__attribute__((address_space(3))) void*)(l), 16, 0, 0);
}

// ---------------- conversion kernels ----------------

// W (1024x1024 fp32) -> W3 [1024][3072] bf16 = [hi | hi | lo]
__global__ void convert_W(const float* __restrict__ W, uint16_t* __restrict__ W3){
  int idx = blockIdx.x * 256 + threadIdx.x;
  int j = idx >> 8;
  int c4 = (idx & 255) * 4;
  float4 v = *(const float4*)(W + (size_t)j * CDIM + c4);
  u16x4 h, lo;
  h.x = f2bf(v.x); lo.x = f2bf(v.x - bf2f(h.x));
  h.y = f2bf(v.y); lo.y = f2bf(v.y - bf2f(h.y));
  h.z = f2bf(v.z); lo.z = f2bf(v.z - bf2f(h.z));
  h.w = f2bf(v.w); lo.w = f2bf(v.w - bf2f(h.w));
  uint16_t* r = W3 + (size_t)j * K3;
  *(u16x4*)(r + c4)        = h;
  *(u16x4*)(r + 1024 + c4) = h;
  *(u16x4*)(r + 2048 + c4) = lo;
}

__global__ void rope_table(float* __restrict__ cosT, float* __restrict__ sinT){
  int t = threadIdx.x;
  if (t < LSEQ * 32){
    int l = t >> 5, i = t & 31;
    float inv = 1.0f / powf(10000.0f, ((float)(2 * i)) / 64.0f);
    float a = (float)l * inv;
    cosT[t] = cosf(a);
    sinT[t] = sinf(a);
  }
}

// A chunk rows (n_local*13 + l) -> hi/lo bf16
__global__ void convert_A(const float* __restrict__ src, uint16_t* __restrict__ Ah,
                          uint16_t* __restrict__ Al, int n0){
  int idx = blockIdx.x * 256 + threadIdx.x;
  int row = idx >> 8;
  int c4 = (idx & 255) * 4;
  int nl = row / 13;
  int l  = row - nl * 13;
  float4 v = *(const float4*)(src + (size_t)l * (NTOK * CDIM) + (size_t)(n0 + nl) * CDIM + c4);
  u16x4 h, lo;
  h.x = f2bf(v.x); lo.x = f2bf(v.x - bf2f(h.x));
  h.y = f2bf(v.y); lo.y = f2bf(v.y - bf2f(h.y));
  h.z = f2bf(v.z); lo.z = f2bf(v.z - bf2f(h.z));
  h.w = f2bf(v.w); lo.w = f2bf(v.w - bf2f(h.w));
  *(u16x4*)(Ah + (size_t)row * CDIM + c4) = h;
  *(u16x4*)(Al + (size_t)row * CDIM + c4) = lo;
}

// Q input rows: only l = 12
__global__ void convert_Aq(const float* __restrict__ src, uint16_t* __restrict__ Ah,
                           uint16_t* __restrict__ Al){
  int idx = blockIdx.x * 256 + threadIdx.x;
  int n = idx >> 8;
  int c4 = (idx & 255) * 4;
  float4 v = *(const float4*)(src + (size_t)12 * (NTOK * CDIM) + (size_t)n * CDIM + c4);
  u16x4 h, lo;
  h.x = f2bf(v.x); lo.x = f2bf(v.x - bf2f(h.x));
  h.y = f2bf(v.y); lo.y = f2bf(v.y - bf2f(h.y));
  h.z = f2bf(v.z); lo.z = f2bf(v.z - bf2f(h.z));
  h.w = f2bf(v.w); lo.w = f2bf(v.w - bf2f(h.w));
  *(u16x4*)(Ah + (size_t)n * CDIM + c4) = h;
  *(u16x4*)(Al + (size_t)n * CDIM + c4) = lo;
}

// ---------------- bf16x3 GEMM (single B) — used for Q and O projections ----------------
__global__ __launch_bounds__(256, 2)
void gemm_x3(const uint16_t* __restrict__ Ahi, const uint16_t* __restrict__ Alo,
             const uint16_t* __restrict__ B3, float* __restrict__ Cout)
{
  __shared__ __align__(16) uint16_t sA[128 * 64];
  __shared__ __align__(16) uint16_t sB[128 * 64];
  const int tid  = threadIdx.x;
  const int lane = tid & 63;
  const int wave = tid >> 6;
  const int arow0 = blockIdx.x * 128;
  const int bcol0 = blockIdx.y * 128;
  const int wr = (wave >> 1) * 64;
  const int wc = (wave & 1) * 64;

  const f32x4 fzero = {0.f, 0.f, 0.f, 0.f};
  f32x4 acc[4][4];
#pragma unroll
  for (int i = 0; i < 4; ++i)
#pragma unroll
    for (int j = 0; j < 4; ++j)
      acc[i][j] = fzero;

  size_t aOff[4], bOff[4];
  int ldsOff[4];
#pragma unroll
  for (int i = 0; i < 4; ++i){
    int o = i * 256 + tid;
    int row = o >> 3;
    int ss = (o & 7) ^ (row & 7);
    aOff[i] = (size_t)(arow0 + row) * CDIM + ss * 8;
    bOff[i] = (size_t)(bcol0 + row) * K3 + ss * 8;
    ldsOff[i] = (i * 256 + wave * 64) * 16;
  }

  int aRd[2][4], bRd[2][4];
#pragma unroll
  for (int ks = 0; ks < 2; ++ks){
    int sw = ((lane >> 4) + ks * 4) ^ (lane & 7);
#pragma unroll
    for (int mi = 0; mi < 4; ++mi){
      aRd[ks][mi] = (wr + mi * 16 + (lane & 15)) * 128 + sw * 16;
      bRd[ks][mi] = (wc + mi * 16 + (lane & 15)) * 128 + sw * 16;
    }
  }

  const char* sAc = (const char*)sA;
  const char* sBc = (const char*)sB;

  for (int step = 0; step < K3 / 64; ++step){
    const int kv0 = step * 64;
    const uint16_t* Abase = ((kv0 >> 10) == 1) ? Alo : Ahi;
    const int kr0 = kv0 & 1023;
#pragma unroll
    for (int i = 0; i < 4; ++i){
      async16(Abase + aOff[i] + kr0, (char*)sA + ldsOff[i]);
      async16(B3    + bOff[i] + kv0, (char*)sB + ldsOff[i]);
    }
    __syncthreads();
#pragma unroll
    for (int ks = 0; ks < 2; ++ks){
      bf16x8 af[4], bfr[4];
#pragma unroll
      for (int mi = 0; mi < 4; ++mi) af[mi]  = *(const bf16x8*)(sAc + aRd[ks][mi]);
#pragma unroll
      for (int ni = 0; ni < 4; ++ni) bfr[ni] = *(const bf16x8*)(sBc + bRd[ks][ni]);
#pragma unroll
      for (int mi = 0; mi < 4; ++mi)
#pragma unroll
        for (int ni = 0; ni < 4; ++ni)
          acc[mi][ni] = __builtin_amdgcn_mfma_f32_16x16x32_bf16(af[mi], bfr[ni], acc[mi][ni], 0, 0, 0);
    }
    __syncthreads();
  }

#pragma unroll
  for (int mi = 0; mi < 4; ++mi){
    const int row = arow0 + wr + mi * 16 + (lane >> 4) * 4;
#pragma unroll
    for (int r = 0; r < 4; ++r){
      float* crow = Cout + (size_t)(row + r) * CDIM + bcol0 + wc + (lane & 15);
#pragma unroll
      for (int ni = 0; ni < 4; ++ni)
        crow[ni * 16] = acc[mi][ni][r];
    }
  }
}

// ---------------- fused dual-B bf16x3 GEMM: K and V share the A tile ----------------
// Doubles MFMA per staged byte: 12 global_load_lds + 64 MFMA per K-step (vs 8+32).
__global__ __launch_bounds__(256, 2)
void gemm_x3_kv(const uint16_t* __restrict__ Ahi, const uint16_t* __restrict__ Alo,
                const uint16_t* __restrict__ Bk3, const uint16_t* __restrict__ Bv3,
                float* __restrict__ Kout, float* __restrict__ Vout)
{
  __shared__ __align__(16) uint16_t sA [128 * 64];
  __shared__ __align__(16) uint16_t sBk[128 * 64];
  __shared__ __align__(16) uint16_t sBv[128 * 64];
  const int tid  = threadIdx.x;
  const int lane = tid & 63;
  const int wave = tid >> 6;
  const int arow0 = blockIdx.x * 128;
  const int bcol0 = blockIdx.y * 128;
  const int wr = (wave >> 1) * 64;
  const int wc = (wave & 1) * 64;

  const f32x4 fzero = {0.f, 0.f, 0.f, 0.f};
  f32x4 acck[4][4], accv[4][4];
#pragma unroll
  for (int i = 0; i < 4; ++i)
#pragma unroll
    for (int j = 0; j < 4; ++j){ acck[i][j] = fzero; accv[i][j] = fzero; }

  size_t aOff[4], bOff[4];
  int ldsOff[4];
#pragma unroll
  for (int i = 0; i < 4; ++i){
    int o = i * 256 + tid;
    int row = o >> 3;
    int ss = (o & 7) ^ (row & 7);              // pre-swizzled source slot (rule #21)
    aOff[i] = (size_t)(arow0 + row) * CDIM + ss * 8;
    bOff[i] = (size_t)(bcol0 + row) * K3 + ss * 8;   // same offsets valid for Bk and Bv
    ldsOff[i] = (i * 256 + wave * 64) * 16;          // wave-uniform LDS base
  }

  int aRd[2][4], bRd[2][4];
#pragma unroll
  for (int ks = 0; ks < 2; ++ks){
    int sw = ((lane >> 4) + ks * 4) ^ (lane & 7);
#pragma unroll
    for (int mi = 0; mi < 4; ++mi){
      aRd[ks][mi] = (wr + mi * 16 + (lane & 15)) * 128 + sw * 16;
      bRd[ks][mi] = (wc + mi * 16 + (lane & 15)) * 128 + sw * 16;
    }
  }

  const char* sAc  = (const char*)sA;
  const char* sBkc = (const char*)sBk;
  const char* sBvc = (const char*)sBv;

  for (int step = 0; step < K3 / 64; ++step){
    const int kv0 = step * 64;
    const uint16_t* Abase = ((kv0 >> 10) == 1) ? Alo : Ahi;
    const int kr0 = kv0 & 1023;
#pragma unroll
    for (int i = 0; i < 4; ++i){
      async16(Abase + aOff[i] + kr0, (char*)sA  + ldsOff[i]);
      async16(Bk3   + bOff[i] + kv0, (char*)sBk + ldsOff[i]);
      async16(Bv3   + bOff[i] + kv0, (char*)sBv + ldsOff[i]);
    }
    __syncthreads();
#pragma unroll
    for (int ks = 0; ks < 2; ++ks){
      bf16x8 af[4], bk[4], bv[4];
#pragma unroll
      for (int mi = 0; mi < 4; ++mi) af[mi] = *(const bf16x8*)(sAc  + aRd[ks][mi]);
#pragma unroll
      for (int ni = 0; ni < 4; ++ni) bk[ni] = *(const bf16x8*)(sBkc + bRd[ks][ni]);
#pragma unroll
      for (int ni = 0; ni < 4; ++ni) bv[ni] = *(const bf16x8*)(sBvc + bRd[ks][ni]);
#pragma unroll
      for (int mi = 0; mi < 4; ++mi)
#pragma unroll
        for (int ni = 0; ni < 4; ++ni){
          acck[mi][ni] = __builtin_amdgcn_mfma_f32_16x16x32_bf16(af[mi], bk[ni], acck[mi][ni], 0, 0, 0);
          accv[mi][ni] = __builtin_amdgcn_mfma_f32_16x16x32_bf16(af[mi], bv[ni], accv[mi][ni], 0, 0, 0);
        }
    }
    __syncthreads();
  }

#pragma unroll
  for (int mi = 0; mi < 4; ++mi){
    const int row = arow0 + wr + mi * 16 + (lane >> 4) * 4;
#pragma unroll
    for (int r = 0; r < 4; ++r){
      float* ck = Kout + (size_t)(row + r) * CDIM + bcol0 + wc + (lane & 15);
      float* cv = Vout + (size_t)(row + r) * CDIM + bcol0 + wc + (lane & 15);
#pragma unroll
      for (int ni = 0; ni < 4; ++ni){
        ck[ni * 16] = acck[mi][ni][r];
        cv[ni * 16] = accv[mi][ni][r];
      }
    }
  }
}

// ---------------- fused RoPE + attention (l = 12 query only) ----------------
__global__ void attn_kernel(const float* __restrict__ Kb, const float* __restrict__ Vb,
                            const float* __restrict__ q, const float* __restrict__ cosT,
                            const float* __restrict__ sinT, uint16_t* __restrict__ ohi,
                            uint16_t* __restrict__ olo, int n0)
{
  int wid  = blockIdx.x * 4 + (threadIdx.x >> 6);
  int lane = threadIdx.x & 63;
  int nl = wid >> 4;
  int h  = wid & 15;
  int d = lane, i = d & 31;

  size_t qoff = (size_t)(n0 + nl) * CDIM + h * 64 + d;
  float qv = q[qoff];
  float qp = __shfl_xor(qv, 32);
  float cq = cosT[12 * 32 + i], sq = sinT[12 * 32 + i];
  float qr = (d < 32) ? (qv * cq - qp * sq) : (qv * cq + qp * sq);

  const float* Kp = Kb + (size_t)nl * (LSEQ * CDIM) + h * 64 + d;
  const float* Vp = Vb + (size_t)nl * (LSEQ * CDIM) + h * 64 + d;

  float s[LSEQ];
#pragma unroll
  for (int m = 0; m < LSEQ; ++m){
    float kv = Kp[m * CDIM];
    float kp = __shfl_xor(kv, 32);
    float cm = cosT[m * 32 + i], sm = sinT[m * 32 + i];
    float kr = (d < 32) ? (kv * cm - kp * sm) : (kv * cm + kp * sm);
    float p = qr * kr;
    p += __shfl_xor(p, 32); p += __shfl_xor(p, 16); p += __shfl_xor(p, 8);
    p += __shfl_xor(p, 4);  p += __shfl_xor(p, 2);  p += __shfl_xor(p, 1);
    s[m] = p * 0.125f;
  }
  float mx = s[0];
#pragma unroll
  for (int m = 1; m < LSEQ; ++m) mx = fmaxf(mx, s[m]);
  float sum = 0.f;
#pragma unroll
  for (int m = 0; m < LSEQ; ++m){ s[m] = expf(s[m] - mx); sum += s[m]; }
  float inv = 1.0f / sum;
  float o = 0.f;
#pragma unroll
  for (int m = 0; m < LSEQ; ++m) o += s[m] * Vp[m * CDIM];
  o *= inv;
  uint16_t hb = f2bf(o);
  uint16_t lb = f2bf(o - bf2f(hb));
  ohi[qoff] = hb;
  olo[qoff] = lb;
}

// ---------------- host ----------------
extern "C" void kernel_launch(void* const* d_in, const int* in_sizes, int n_in,
                              void* d_out, int out_size, void* d_ws, size_t ws_size,
                              hipStream_t stream)
{
  (void)in_sizes; (void)n_in; (void)out_size;
  const float* src = (const float*)d_in[0];
  const float* Wq  = (const float*)d_in[1];
  const float* Wk  = (const float*)d_in[2];
  const float* Wv  = (const float*)d_in[3];
  const float* Wo  = (const float*)d_in[4];
  float* out = (float*)d_out;

  // adaptive chunk over tokens (cn >=128 so cn*13 divides by the 128-row GEMM tile)
  int cn = 1024;
  while (cn > 128 && (75501056ull + 4096ull + (size_t)cn * 159744ull) > ws_size) cn >>= 1;
  const int nchunks = NTOK / cn;

  char* p = (char*)d_ws;
  auto carve = [&](size_t bytes) -> void* {
    void* r = (void*)p; p += (bytes + 255) & ~(size_t)255; return r;
  };
  uint16_t* W3q = (uint16_t*)carve((size_t)CDIM * K3 * 2);
  uint16_t* W3k = (uint16_t*)carve((size_t)CDIM * K3 * 2);
  uint16_t* W3v = (uint16_t*)carve((size_t)CDIM * K3 * 2);
  uint16_t* W3o = (uint16_t*)carve((size_t)CDIM * K3 * 2);
  float* cosT = (float*)carve(LSEQ * 32 * 4);
  float* sinT = (float*)carve(LSEQ * 32 * 4);
  uint16_t* Aqh = (uint16_t*)carve((size_t)NTOK * CDIM * 2);
  uint16_t* Aql = (uint16_t*)carve((size_t)NTOK * CDIM * 2);
  float* qbuf   = (float*)carve((size_t)NTOK * CDIM * 4);
  uint16_t* ohi = (uint16_t*)carve((size_t)NTOK * CDIM * 2);
  uint16_t* olo = (uint16_t*)carve((size_t)NTOK * CDIM * 2);
  uint16_t* Ah  = (uint16_t*)carve((size_t)cn * LSEQ * CDIM * 2);
  uint16_t* Al  = (uint16_t*)carve((size_t)cn * LSEQ * CDIM * 2);
  float* Kb     = (float*)carve((size_t)cn * LSEQ * CDIM * 4);
  float* Vb     = (float*)carve((size_t)cn * LSEQ * CDIM * 4);

  convert_W<<<1024, 256, 0, stream>>>(Wq, W3q);
  convert_W<<<1024, 256, 0, stream>>>(Wk, W3k);
  convert_W<<<1024, 256, 0, stream>>>(Wv, W3v);
  convert_W<<<1024, 256, 0, stream>>>(Wo, W3o);
  rope_table<<<1, 512, 0, stream>>>(cosT, sinT);
  convert_Aq<<<NTOK, 256, 0, stream>>>(src, Aqh, Aql);
  gemm_x3<<<dim3(NTOK / 128, 8), 256, 0, stream>>>(Aqh, Aql, W3q, qbuf);

  for (int c = 0; c < nchunks; ++c){
    convert_A<<<cn * LSEQ, 256, 0, stream>>>(src, Ah, Al, c * cn);
    gemm_x3_kv<<<dim3(cn * LSEQ / 128, 8), 256, 0, stream>>>(Ah, Al, W3k, W3v, Kb, Vb);
    attn_kernel<<<cn * 4, 256, 0, stream>>>(Kb, Vb, qbuf, cosT, sinT, ohi, olo, c * cn);
  }
  gemm_x3<<<dim3(NTOK / 128, 8), 256, 0, stream>>>(ohi, olo, W3o, out);
}